// Round 1
// baseline (10294.773 us; speedup 1.0000x reference)
//
#include <hip/hip_runtime.h>
#include <math.h>

// HyperLSTM fp32 reference-quality implementation (round 1: correctness + decent tiling).
// T=64, B=64, dims: layer0 400->1150, layer1 1150->1150, layer2 1150->400, decoder K=400 N=33278.

#define LDX 1152      // padded feature stride (>=1150, mult of 16)
#define LDG 4608      // padded gate stride (4*1152)
#define TKK 16        // K tile

// ---------------------------------------------------------------- embed
__global__ __launch_bounds__(256) void k_embed(
    const int* __restrict__ tokens, const float* __restrict__ hnet,
    const float* __restrict__ elem_emb, const float* __restrict__ hnet_emb,
    const float* __restrict__ embS, float* __restrict__ xA)
{
    int r = blockIdx.x;           // 0..4095  (r = t*64 + b)
    int b = r & 63;
    int tok = tokens[r];
    float hv[7];
#pragma unroll
    for (int q = 0; q < 7; ++q) hv[q] = hnet[b * 7 + q];
    for (int j = threadIdx.x; j < LDX; j += 256) {
        float v = 0.f;
        if (j < 400) {
            float sc = 0.f;
#pragma unroll
            for (int q = 0; q < 7; ++q) sc += hv[q] * embS[j * 7 + q];
            v = elem_emb[(long)tok * 400 + j] + sc * hnet_emb[(long)tok * 400 + j];
        }
        xA[(long)r * LDX + j] = v;
    }
}

// zero pad columns (1150,1151) of an x buffer so K-padded GEMMs read zeros
__global__ void k_zero_pads(float* __restrict__ xB)
{
    int r = blockIdx.x * blockDim.x + threadIdx.x;
    if (r < 4096) {
        xB[(long)r * LDX + 1150] = 0.f;
        xB[(long)r * LDX + 1151] = 0.f;
    }
}

// ---------------------------------------------------------------- hyper scales + bias
__global__ __launch_bounds__(256) void k_scales(
    const float* __restrict__ hnet,
    const float* __restrict__ Si, const float* __restrict__ bei, const float* __restrict__ bhi,
    const float* __restrict__ Sh, const float* __restrict__ beh, const float* __restrict__ bhh,
    int n, float* __restrict__ wsI, float* __restrict__ wsH, float* __restrict__ biasb)
{
    int idx = blockIdx.x * 256 + threadIdx.x;
    if (idx >= 64 * LDG) return;
    int b = idx / LDG, j = idx - b * LDG;
    int n4 = 4 * n;
    float wi = 0.f, wh = 0.f, bi = 0.f;
    if (j < n4) {
        float bsi = 0.f, bsh = 0.f;
#pragma unroll
        for (int q = 0; q < 7; ++q) {
            float h = hnet[b * 7 + q];
            wi  += h * Si[(long)j * 7 + q];
            bsi += h * Si[(long)(n4 + j) * 7 + q];
            wh  += h * Sh[(long)j * 7 + q];
            bsh += h * Sh[(long)(n4 + j) * 7 + q];
        }
        bi = bei[j] + bsi * bhi[j] + beh[j] + bsh * bhh[j];
    }
    wsI[idx] = wi; wsH[idx] = wh; biasb[idx] = bi;
}

// ---------------------------------------------------------------- h/c init (with zero pads)
__global__ void k_init_state(const float* __restrict__ h0, const float* __restrict__ c0,
                             int n, float* __restrict__ h, float* __restrict__ c)
{
    int idx = blockIdx.x * blockDim.x + threadIdx.x;
    if (idx >= 64 * LDX) return;
    int b = idx / LDX, j = idx - b * LDX;
    float hv = 0.f, cv = 0.f;
    if (j < n) { hv = h0[b * n + j]; cv = c0[b * n + j]; }
    h[idx] = hv; c[idx] = cv;
}

// ---------------------------------------------------------------- input projection GEMM
// preX[r][jj] = dot(x[r,:],We[jj,:]) + wsI[b][jj]*dot(x[r,:],Wh[jj,:]) + bias[b][jj]
__global__ __launch_bounds__(256) void k_input_gemm(
    const float* __restrict__ A,                          // 4096 x LDX
    const float* __restrict__ Be, const float* __restrict__ Bh,  // n4 x ldb
    const float* __restrict__ wsI, const float* __restrict__ biasb,
    float* __restrict__ preX,
    int Kpad, int ldb, int n4)
{
    __shared__ __align__(16) float sA[TKK][68], sBe[TKK][68], sBh[TKK][68];
    int m0 = blockIdx.x * 64;
    int n0 = blockIdx.y * 64;
    int tid = threadIdx.x;
    int tx = tid & 15, ty = tid >> 4;
    float accE[4][4] = {{0.f}}, accH[4][4] = {{0.f}};
    long bmax = (long)n4 * ldb - 1;
    for (int k0 = 0; k0 < Kpad; k0 += TKK) {
#pragma unroll
        for (int i = 0; i < 4; ++i) {
            int e = tid + 256 * i;
            int kk = e & 15, mm = e >> 4;
            sA[kk][mm] = A[(long)(m0 + mm) * LDX + k0 + kk];
            int row = n0 + mm; if (row > n4 - 1) row = n4 - 1;
            long bidx = (long)row * ldb + k0 + kk;
            if (bidx > bmax) bidx = bmax;      // k-pad reads garbage*0 (A pad is 0), clamped in-bounds
            sBe[kk][mm] = Be[bidx];
            sBh[kk][mm] = Bh[bidx];
        }
        __syncthreads();
#pragma unroll
        for (int k = 0; k < TKK; ++k) {
            float4 a4 = *(const float4*)&sA[k][ty * 4];
            float4 e4 = *(const float4*)&sBe[k][tx * 4];
            float4 h4 = *(const float4*)&sBh[k][tx * 4];
            float av[4] = {a4.x, a4.y, a4.z, a4.w};
            float ev[4] = {e4.x, e4.y, e4.z, e4.w};
            float hv[4] = {h4.x, h4.y, h4.z, h4.w};
#pragma unroll
            for (int i = 0; i < 4; ++i)
#pragma unroll
                for (int j = 0; j < 4; ++j) {
                    accE[i][j] += av[i] * ev[j];
                    accH[i][j] += av[i] * hv[j];
                }
        }
        __syncthreads();
    }
#pragma unroll
    for (int i = 0; i < 4; ++i) {
        int r = m0 + ty * 4 + i;
        int b = r & 63;
        int jj0 = n0 + tx * 4;
        float4 o;
        o.x = accE[i][0] + wsI[b * LDG + jj0 + 0] * accH[i][0] + biasb[b * LDG + jj0 + 0];
        o.y = accE[i][1] + wsI[b * LDG + jj0 + 1] * accH[i][1] + biasb[b * LDG + jj0 + 1];
        o.z = accE[i][2] + wsI[b * LDG + jj0 + 2] * accH[i][2] + biasb[b * LDG + jj0 + 2];
        o.w = accE[i][3] + wsI[b * LDG + jj0 + 3] * accH[i][3] + biasb[b * LDG + jj0 + 3];
        *(float4*)&preX[(long)r * LDG + jj0] = o;
    }
}

// ---------------------------------------------------------------- recurrent partial GEMM (K-split)
__global__ __launch_bounds__(256) void k_rec_gemm(
    const float* __restrict__ h,                           // 64 x LDX
    const float* __restrict__ Be, const float* __restrict__ Bh,  // n4 x ldb (ldb = n)
    float* __restrict__ partE, float* __restrict__ partH,
    int kchunk, int ldb, int n4)
{
    __shared__ __align__(16) float sA[TKK][68], sBe[TKK][68], sBh[TKK][68];
    int n0 = blockIdx.x * 64;
    int ks = blockIdx.y;
    int tid = threadIdx.x;
    int tx = tid & 15, ty = tid >> 4;
    float accE[4][4] = {{0.f}}, accH[4][4] = {{0.f}};
    long bmax = (long)n4 * ldb - 1;
    int kbeg = ks * kchunk, kend = kbeg + kchunk;
    for (int k0 = kbeg; k0 < kend; k0 += TKK) {
#pragma unroll
        for (int i = 0; i < 4; ++i) {
            int e = tid + 256 * i;
            int kk = e & 15, mm = e >> 4;
            sA[kk][mm] = h[(long)mm * LDX + k0 + kk];
            int row = n0 + mm; if (row > n4 - 1) row = n4 - 1;
            long bidx = (long)row * ldb + k0 + kk;
            if (bidx > bmax) bidx = bmax;
            sBe[kk][mm] = Be[bidx];
            sBh[kk][mm] = Bh[bidx];
        }
        __syncthreads();
#pragma unroll
        for (int k = 0; k < TKK; ++k) {
            float4 a4 = *(const float4*)&sA[k][ty * 4];
            float4 e4 = *(const float4*)&sBe[k][tx * 4];
            float4 h4 = *(const float4*)&sBh[k][tx * 4];
            float av[4] = {a4.x, a4.y, a4.z, a4.w};
            float ev[4] = {e4.x, e4.y, e4.z, e4.w};
            float hv[4] = {h4.x, h4.y, h4.z, h4.w};
#pragma unroll
            for (int i = 0; i < 4; ++i)
#pragma unroll
                for (int j = 0; j < 4; ++j) {
                    accE[i][j] += av[i] * ev[j];
                    accH[i][j] += av[i] * hv[j];
                }
        }
        __syncthreads();
    }
#pragma unroll
    for (int i = 0; i < 4; ++i) {
        int r = ty * 4 + i;
        int jj0 = n0 + tx * 4;
        float4 oe = make_float4(accE[i][0], accE[i][1], accE[i][2], accE[i][3]);
        float4 oh = make_float4(accH[i][0], accH[i][1], accH[i][2], accH[i][3]);
        *(float4*)&partE[((long)ks * 64 + r) * LDG + jj0] = oe;
        *(float4*)&partH[((long)ks * 64 + r) * LDG + jj0] = oh;
    }
}

// ---------------------------------------------------------------- gates + state update
__global__ __launch_bounds__(256) void k_gates(
    const float* __restrict__ partE, const float* __restrict__ partH, int KS,
    const float* __restrict__ preX, const float* __restrict__ wsH,
    float* __restrict__ c, float* __restrict__ h, float* __restrict__ xout,
    int n, int t)
{
    int idx = blockIdx.x * 256 + threadIdx.x;
    if (idx >= 64 * n) return;
    int b = idx / n, j = idx - b * n;
    float pre[4];
#pragma unroll
    for (int g = 0; g < 4; ++g) {
        int jj = g * n + j;
        float se = 0.f, sh = 0.f;
        for (int ks = 0; ks < KS; ++ks) {
            se += partE[((long)ks * 64 + b) * LDG + jj];
            sh += partH[((long)ks * 64 + b) * LDG + jj];
        }
        pre[g] = preX[((long)(t * 64 + b)) * LDG + jj] + se + wsH[b * LDG + jj] * sh;
    }
    float f  = 1.f / (1.f + expf(-pre[0]));
    float ii = 1.f / (1.f + expf(-pre[1]));
    float o  = 1.f / (1.f + expf(-pre[2]));
    float g_ = tanhf(pre[3]);
    float cv = f * c[b * LDX + j] + ii * g_;
    float hv = o * tanhf(cv);
    c[b * LDX + j] = cv;
    h[b * LDX + j] = hv;
    xout[((long)(t * 64 + b)) * LDX + j] = hv;
}

// ---------------------------------------------------------------- decoder GEMM
__global__ __launch_bounds__(256) void k_decoder(
    const float* __restrict__ A,      // 4096 x LDX (first 400 cols valid)
    const float* __restrict__ E,      // 33278 x 400
    const float* __restrict__ dbias,
    float* __restrict__ out)
{
    __shared__ __align__(16) float sA[TKK][68], sB[TKK][68];
    int m0 = blockIdx.x * 64, n0 = blockIdx.y * 64;
    int tid = threadIdx.x, tx = tid & 15, ty = tid >> 4;
    float acc[4][4] = {{0.f}};
    for (int k0 = 0; k0 < 400; k0 += TKK) {
#pragma unroll
        for (int i = 0; i < 4; ++i) {
            int e = tid + 256 * i;
            int kk = e & 15, mm = e >> 4;
            sA[kk][mm] = A[(long)(m0 + mm) * LDX + k0 + kk];
            int row = n0 + mm; if (row > 33277) row = 33277;
            sB[kk][mm] = E[(long)row * 400 + k0 + kk];
        }
        __syncthreads();
#pragma unroll
        for (int k = 0; k < TKK; ++k) {
            float4 a4 = *(const float4*)&sA[k][ty * 4];
            float av[4] = {a4.x, a4.y, a4.z, a4.w};
#pragma unroll
            for (int j = 0; j < 4; ++j) {
                float bv = sB[k][tx + 16 * j];   // strided cols -> coalesced scalar stores
#pragma unroll
                for (int i = 0; i < 4; ++i) acc[i][j] += av[i] * bv;
            }
        }
        __syncthreads();
    }
#pragma unroll
    for (int i = 0; i < 4; ++i) {
        int r = m0 + ty * 4 + i;
#pragma unroll
        for (int j = 0; j < 4; ++j) {
            int v = n0 + tx + 16 * j;
            if (v < 33278) out[(long)r * 33278 + v] = acc[i][j] + dbias[v];
        }
    }
}

// ---------------------------------------------------------------- host
extern "C" void kernel_launch(void* const* d_in, const int* in_sizes, int n_in,
                              void* d_out, int out_size, void* d_ws, size_t ws_size,
                              hipStream_t stream)
{
    const int*   tokens   = (const int*)d_in[0];
    const float* hnet     = (const float*)d_in[1];
    const float* elem_emb = (const float*)d_in[2];
    const float* hnet_emb = (const float*)d_in[3];
    const float* embS     = (const float*)d_in[4];
    const float* dec_bias = (const float*)d_in[41];
    float* out = (float*)d_out;

    // scratch carve (all sizes in floats)
    const size_t SZ_X    = (size_t)4096 * LDX;   // 4,718,592
    const size_t SZ_PRE  = (size_t)4096 * LDG;   // 18,874,368
    const size_t SZ_PART = (size_t)8 * 64 * LDG; // 2,359,296
    const size_t SZ_WS64 = (size_t)64 * LDG;     // 294,912
    const size_t SZ_HC   = (size_t)64 * LDX;     // 73,728

    float* ws = (float*)d_ws;
    // smalls + decoder-input buffer MUST be in ws (decoder writes all of d_out)
    float* xB    = ws;
    float* wsI   = xB + SZ_X;
    float* wsH   = wsI + SZ_WS64;
    float* biasb = wsH + SZ_WS64;
    float* hbuf  = biasb + SZ_WS64;
    float* cbuf  = hbuf + SZ_HC;
    size_t small_need = SZ_X + 3 * SZ_WS64 + 2 * SZ_HC;
    size_t big_need   = SZ_X + SZ_PRE + 2 * SZ_PART;
    float *xA, *preX, *partE, *partH;
    if (ws_size / 4 >= small_need + big_need) {
        xA    = cbuf + SZ_HC;
        preX  = xA + SZ_X;
        partE = preX + SZ_PRE;
        partH = partE + SZ_PART;
    } else {
        // carve the tail of d_out: these buffers are dead before the decoder runs
        float* tail = out + (size_t)out_size;
        partH = tail - SZ_PART;
        partE = partH - SZ_PART;
        preX  = partE - SZ_PRE;
        xA    = preX - SZ_X;
    }

    k_embed<<<4096, 256, 0, stream>>>(tokens, hnet, elem_emb, hnet_emb, embS, xA);
    k_zero_pads<<<16, 256, 0, stream>>>(xB);

    const int DIN[3] = {400, 1150, 1150};
    const int NN[3]  = {1150, 1150, 400};
    float* xin = xA;
    float* xout = xB;
    for (int l = 0; l < 3; ++l) {
        const float* We_i = (const float*)d_in[5 + 12 * l + 0];
        const float* Wh_i = (const float*)d_in[5 + 12 * l + 1];
        const float* be_i = (const float*)d_in[5 + 12 * l + 2];
        const float* bh_i = (const float*)d_in[5 + 12 * l + 3];
        const float* S_i  = (const float*)d_in[5 + 12 * l + 4];
        const float* We_h = (const float*)d_in[5 + 12 * l + 5];
        const float* Wh_h = (const float*)d_in[5 + 12 * l + 6];
        const float* be_h = (const float*)d_in[5 + 12 * l + 7];
        const float* bh_h = (const float*)d_in[5 + 12 * l + 8];
        const float* S_h  = (const float*)d_in[5 + 12 * l + 9];
        const float* h0   = (const float*)d_in[5 + 12 * l + 10];
        const float* c0   = (const float*)d_in[5 + 12 * l + 11];
        int n = NN[l], din = DIN[l], n4 = 4 * n;
        int Kpad_in  = (din == 400) ? 400 : 1152;
        int Kpad_rec = (n == 1150) ? 1152 : 400;
        int Ntiles = (n4 + 63) / 64;              // 72 or 25
        int KS = (n == 1150) ? 8 : 5;
        int kchunk = Kpad_rec / KS;               // 144 or 80

        k_scales<<<(64 * LDG + 255) / 256, 256, 0, stream>>>(
            hnet, S_i, be_i, bh_i, S_h, be_h, bh_h, n, wsI, wsH, biasb);
        k_init_state<<<(64 * LDX + 255) / 256, 256, 0, stream>>>(h0, c0, n, hbuf, cbuf);
        k_input_gemm<<<dim3(64, Ntiles), 256, 0, stream>>>(
            xin, We_i, Wh_i, wsI, biasb, preX, Kpad_in, din, n4);
        for (int t = 0; t < 64; ++t) {
            k_rec_gemm<<<dim3(Ntiles, KS), 256, 0, stream>>>(
                hbuf, We_h, Wh_h, partE, partH, kchunk, n, n4);
            k_gates<<<(64 * n + 255) / 256, 256, 0, stream>>>(
                partE, partH, KS, preX, wsH, cbuf, hbuf, xout, n, t);
        }
        float* tmp = xin; xin = xout; xout = tmp;
    }
    // after 3 swaps xin == xB (in ws): safe while decoder overwrites all of d_out
    k_decoder<<<dim3(64, 520), 256, 0, stream>>>(xin, elem_emb, dec_bias, out);
}